// Round 2
// baseline (851.277 us; speedup 1.0000x reference)
//
#include <hip/hip_runtime.h>
#include <hip/hip_bf16.h>

#define N_NODES 100000
#define N_EDGES 1600000
#define NEG_SLOPE 0.2f

// ---------------- precompute M1[16][8], M2[16] ----------------
__global__ void k_pre(const float* __restrict__ We1, const float* __restrict__ attE1,
                      const float* __restrict__ We2, const float* __restrict__ attE2,
                      float* __restrict__ M1, float* __restrict__ M2) {
    int t = threadIdx.x;
    if (t < 128) {
        int d = t >> 3, h = t & 7;
        float s = 0.f;
        for (int c = 0; c < 16; ++c) s += We1[d * 128 + h * 16 + c] * attE1[h * 16 + c];
        M1[d * 8 + h] = s;   // layout [d][h]
    } else if (t < 144) {
        int d = t - 128;
        float s = 0.f;
        for (int c = 0; c < 16; ++c) s += We2[d * 16 + c] * attE2[c];
        M2[d] = s;
    }
}

// ---------------- GEMM1: xh1 = x @ W1, plus a1s/a1d ----------------
__global__ __launch_bounds__(256) void k_gemm1(
    const float* __restrict__ x, const float* __restrict__ W1,
    const float* __restrict__ attS, const float* __restrict__ attD,
    float* __restrict__ xh1, float* __restrict__ a1s, float* __restrict__ a1d) {
    __shared__ float Ws[128 * 128];
    int tid = threadIdx.x;
    for (int i = tid * 4; i < 16384; i += 1024)
        *(float4*)(Ws + i) = *(const float4*)(W1 + i);
    __syncthreads();
    int tx = tid & 31, ty = tid >> 5;
    int r0 = blockIdx.x * 16 + ty;     // and r0+8
    int c0 = tx * 4;
    const float* xr0 = x + (size_t)r0 * 128;
    const float* xr1 = xr0 + 8 * 128;
    float acc0[4] = {0.f, 0.f, 0.f, 0.f};
    float acc1[4] = {0.f, 0.f, 0.f, 0.f};
    for (int k = 0; k < 128; k += 4) {
        float4 xa4 = *(const float4*)(xr0 + k);
        float4 xb4 = *(const float4*)(xr1 + k);
        float xa[4] = {xa4.x, xa4.y, xa4.z, xa4.w};
        float xb[4] = {xb4.x, xb4.y, xb4.z, xb4.w};
#pragma unroll
        for (int j = 0; j < 4; ++j) {
            float4 w = *(const float4*)(Ws + (k + j) * 128 + c0);
            acc0[0] += xa[j] * w.x; acc0[1] += xa[j] * w.y;
            acc0[2] += xa[j] * w.z; acc0[3] += xa[j] * w.w;
            acc1[0] += xb[j] * w.x; acc1[1] += xb[j] * w.y;
            acc1[2] += xb[j] * w.z; acc1[3] += xb[j] * w.w;
        }
    }
    float4 o0 = {acc0[0], acc0[1], acc0[2], acc0[3]};
    float4 o1 = {acc1[0], acc1[1], acc1[2], acc1[3]};
    *(float4*)(xh1 + (size_t)r0 * 128 + c0) = o0;
    *(float4*)(xh1 + (size_t)(r0 + 8) * 128 + c0) = o1;
    int h = tx >> 2;
    int cc = (tx & 3) * 4;
    float ps0 = 0.f, pd0 = 0.f, ps1 = 0.f, pd1 = 0.f;
#pragma unroll
    for (int j = 0; j < 4; ++j) {
        float aS = attS[h * 16 + cc + j];
        float aD = attD[h * 16 + cc + j];
        ps0 += acc0[j] * aS; pd0 += acc0[j] * aD;
        ps1 += acc1[j] * aS; pd1 += acc1[j] * aD;
    }
    ps0 += __shfl_xor(ps0, 1); ps0 += __shfl_xor(ps0, 2);
    pd0 += __shfl_xor(pd0, 1); pd0 += __shfl_xor(pd0, 2);
    ps1 += __shfl_xor(ps1, 1); ps1 += __shfl_xor(ps1, 2);
    pd1 += __shfl_xor(pd1, 1); pd1 += __shfl_xor(pd1, 2);
    if ((tx & 3) == 0) {
        a1s[(size_t)r0 * 8 + h] = ps0;       a1d[(size_t)r0 * 8 + h] = pd0;
        a1s[(size_t)(r0 + 8) * 8 + h] = ps1; a1d[(size_t)(r0 + 8) * 8 + h] = pd1;
    }
}

// ---------------- CSR build ----------------
__global__ void k_hist(const int* __restrict__ dst, int* __restrict__ count) {
    int i = blockIdx.x * blockDim.x + threadIdx.x;
    if (i < N_EDGES) atomicAdd(&count[dst[i]], 1);
}

__global__ __launch_bounds__(256) void k_scan1(const int* __restrict__ count,
                                               int* __restrict__ offs, int* __restrict__ partials) {
    __shared__ int s[256];
    int t = threadIdx.x;
    int i = blockIdx.x * 256 + t;
    int v = (i < N_NODES) ? count[i] : 0;
    s[t] = v; __syncthreads();
    for (int off = 1; off < 256; off <<= 1) {
        int add = (t >= off) ? s[t - off] : 0;
        __syncthreads();
        s[t] += add; __syncthreads();
    }
    if (i < N_NODES) offs[i] = s[t] - v;
    if (t == 255) partials[blockIdx.x] = s[255];
}

__global__ __launch_bounds__(512) void k_scan2(int* __restrict__ partials, int nb) {
    __shared__ int s[512];
    int t = threadIdx.x;
    int v = (t < nb) ? partials[t] : 0;
    s[t] = v; __syncthreads();
    for (int off = 1; off < 512; off <<= 1) {
        int add = (t >= off) ? s[t - off] : 0;
        __syncthreads();
        s[t] += add; __syncthreads();
    }
    if (t < nb) partials[t] = s[t] - v;
}

__global__ void k_scan3(int* __restrict__ offs, const int* __restrict__ partials) {
    int i = blockIdx.x * 256 + threadIdx.x;
    if (i < N_NODES) offs[i] += partials[blockIdx.x];
}

// ---------------- k_attn: edge-order streaming, fully coalesced outputs ----------------
__global__ __launch_bounds__(256) void k_attn(
    const int* __restrict__ src, const int* __restrict__ dst,
    const float* __restrict__ ea, const float* __restrict__ M1, const float* __restrict__ M2,
    const float* __restrict__ a1s, const float* __restrict__ a1d,
    float* __restrict__ ew1, float* __restrict__ ae2) {
    __shared__ float M1s[128], M2s[16];
    int t = threadIdx.x;
    if (t < 128) M1s[t] = M1[t];
    if (t >= 128 && t < 144) M2s[t - 128] = M2[t - 128];
    __syncthreads();
    int e = blockIdx.x * 256 + t;
    int s = src[e], d = dst[e];
    float eav[16];
#pragma unroll
    for (int q = 0; q < 4; ++q) {
        float4 v = *(const float4*)(ea + (size_t)e * 16 + q * 4);
        eav[q * 4] = v.x; eav[q * 4 + 1] = v.y; eav[q * 4 + 2] = v.z; eav[q * 4 + 3] = v.w;
    }
    float ae1[8];
#pragma unroll
    for (int h = 0; h < 8; ++h) ae1[h] = 0.f;
#pragma unroll
    for (int dd = 0; dd < 16; ++dd) {
#pragma unroll
        for (int h = 0; h < 8; ++h) ae1[h] += eav[dd] * M1s[dd * 8 + h];
    }
    float aes = 0.f;
#pragma unroll
    for (int dd = 0; dd < 16; ++dd) aes += eav[dd] * M2s[dd];
    float4 s0 = *(const float4*)(a1s + (size_t)s * 8);
    float4 s1 = *(const float4*)(a1s + (size_t)s * 8 + 4);
    float4 d0 = *(const float4*)(a1d + (size_t)d * 8);
    float4 d1 = *(const float4*)(a1d + (size_t)d * 8 + 4);
    float as_[8] = {s0.x, s0.y, s0.z, s0.w, s1.x, s1.y, s1.z, s1.w};
    float ad_[8] = {d0.x, d0.y, d0.z, d0.w, d1.x, d1.y, d1.z, d1.w};
    float ew[8];
#pragma unroll
    for (int h = 0; h < 8; ++h) {
        float v = as_[h] + ad_[h] + ae1[h];
        v = v > 0.f ? v : NEG_SLOPE * v;
        ew[h] = __expf(v);
    }
    float4 w0 = {ew[0], ew[1], ew[2], ew[3]};
    float4 w1 = {ew[4], ew[5], ew[6], ew[7]};
    *(float4*)(ew1 + (size_t)e * 8) = w0;
    *(float4*)(ew1 + (size_t)e * 8 + 4) = w1;
    ae2[e] = aes;
}

// ---------------- k_scatter: 4-byte permutation scatter only ----------------
__global__ __launch_bounds__(256) void k_scatter(
    const int* __restrict__ dst, const int* __restrict__ offs,
    int* __restrict__ cursor, int* __restrict__ eid) {
    int e = blockIdx.x * 256 + threadIdx.x;
    int d = dst[e];
    int p = offs[d] + atomicAdd(&cursor[d], 1);
    eid[p] = e;
}

// ---------------- layer-1 aggregation: block per node, 128 threads ----------------
__global__ __launch_bounds__(128) void k_agg1(
    const int* __restrict__ eid, const int* __restrict__ src, const float* __restrict__ ew1,
    const float* __restrict__ xh1, const int* __restrict__ offs, const int* __restrict__ count,
    const float* __restrict__ b1, float* __restrict__ h1) {
    int n = blockIdx.x;
    int c = threadIdx.x;
    int h = c >> 4;
    int start = offs[n], deg = count[n];
    float acc = 0.f, wsum = 0.f;
    int i = 0;
    for (; i + 4 <= deg; i += 4) {
        int p = start + i;
        int e0 = eid[p], e1 = eid[p + 1], e2 = eid[p + 2], e3 = eid[p + 3];
        int s0 = src[e0], s1 = src[e1], s2 = src[e2], s3 = src[e3];
        float w0 = ew1[(size_t)e0 * 8 + h], w1 = ew1[(size_t)e1 * 8 + h];
        float w2 = ew1[(size_t)e2 * 8 + h], w3 = ew1[(size_t)e3 * 8 + h];
        float x0 = xh1[(size_t)s0 * 128 + c], x1 = xh1[(size_t)s1 * 128 + c];
        float x2 = xh1[(size_t)s2 * 128 + c], x3 = xh1[(size_t)s3 * 128 + c];
        acc += w0 * x0; acc += w1 * x1; acc += w2 * x2; acc += w3 * x3;
        wsum += w0 + w1 + w2 + w3;
    }
    for (; i < deg; ++i) {
        int p = start + i;
        int e = eid[p];
        int s = src[e];
        float w = ew1[(size_t)e * 8 + h];
        acc += w * xh1[(size_t)s * 128 + c];
        wsum += w;
    }
    float v = acc / (wsum + 1e-16f) + b1[c];
    h1[(size_t)n * 128 + c] = v > 0.f ? v : __expf(v) - 1.f;
}

// ---------------- GEMM2: xh2 = h1 @ W2, plus a2s/a2d ----------------
__global__ __launch_bounds__(256) void k_gemm2(
    const float* __restrict__ h1, const float* __restrict__ W2,
    const float* __restrict__ attS, const float* __restrict__ attD,
    float* __restrict__ xh2, float* __restrict__ a2s, float* __restrict__ a2d) {
    __shared__ float W2s[128 * 16];
    __shared__ float hs[16 * 132];   // +4 pad to break bank conflicts
    int t = threadIdx.x;
    for (int i = t * 4; i < 2048; i += 1024)
        *(float4*)(W2s + i) = *(const float4*)(W2 + i);
    size_t base = (size_t)blockIdx.x * 16 * 128;
    for (int i = t * 4; i < 2048; i += 1024) {
        float4 v = *(const float4*)(h1 + base + i);
        int r = i >> 7, k = i & 127;
        float* dstp = hs + r * 132 + k;
        dstp[0] = v.x; dstp[1] = v.y; dstp[2] = v.z; dstp[3] = v.w;
    }
    __syncthreads();
    int r = t >> 4, c = t & 15;
    float acc = 0.f;
#pragma unroll 4
    for (int k = 0; k < 128; ++k) acc += hs[r * 132 + k] * W2s[k * 16 + c];
    int row = blockIdx.x * 16 + r;
    xh2[(size_t)row * 16 + c] = acc;
    float ps = acc * attS[c], pd = acc * attD[c];
#pragma unroll
    for (int m = 1; m < 16; m <<= 1) { ps += __shfl_xor(ps, m); pd += __shfl_xor(pd, m); }
    if (c == 0) { a2s[row] = ps; a2d[row] = pd; }
}

// ---------------- layer-2 aggregation + bias + log_softmax ----------------
__global__ __launch_bounds__(64) void k_agg2(
    const int* __restrict__ eid, const int* __restrict__ src, const float* __restrict__ ae2,
    const float* __restrict__ a2s, const float* __restrict__ a2d, const float* __restrict__ xh2,
    const int* __restrict__ offs, const int* __restrict__ count,
    const float* __restrict__ b2, float* __restrict__ out) {
    int n = blockIdx.x;
    int t = threadIdx.x;
    int j = t >> 4, c = t & 15;
    int start = offs[n], deg = count[n];
    float ad = a2d[n];
    float acc = 0.f, wsum = 0.f;
    for (int i = j; i < deg; i += 4) {
        int p = start + i;
        int e = eid[p];
        int s = src[e];
        float lg = a2s[s] + ad + ae2[e];
        lg = lg > 0.f ? lg : NEG_SLOPE * lg;
        float w = __expf(lg);
        acc += w * xh2[(size_t)s * 16 + c];
        wsum += w;
    }
    acc += __shfl_xor(acc, 16);  acc += __shfl_xor(acc, 32);
    wsum += __shfl_xor(wsum, 16); wsum += __shfl_xor(wsum, 32);
    float logit = acc / (wsum + 1e-16f) + b2[c];
    float m = logit;
#pragma unroll
    for (int mm = 1; mm < 16; mm <<= 1) m = fmaxf(m, __shfl_xor(m, mm));
    float ex = __expf(logit - m);
#pragma unroll
    for (int mm = 1; mm < 16; mm <<= 1) ex += __shfl_xor(ex, mm);
    float res = logit - m - __logf(ex);
    if (t < 16) out[(size_t)n * 16 + c] = res;
}

extern "C" void kernel_launch(void* const* d_in, const int* in_sizes, int n_in,
                              void* d_out, int out_size, void* d_ws, size_t ws_size,
                              hipStream_t stream) {
    const float* x     = (const float*)d_in[0];
    const int*   ei    = (const int*)d_in[1];
    const float* ea    = (const float*)d_in[2];
    const float* W1    = (const float*)d_in[3];
    const float* attS1 = (const float*)d_in[4];
    const float* attD1 = (const float*)d_in[5];
    const float* We1   = (const float*)d_in[6];
    const float* attE1 = (const float*)d_in[7];
    const float* b1    = (const float*)d_in[8];
    const float* W2    = (const float*)d_in[9];
    const float* attS2 = (const float*)d_in[10];
    const float* attD2 = (const float*)d_in[11];
    const float* We2   = (const float*)d_in[12];
    const float* attE2 = (const float*)d_in[13];
    const float* b2    = (const float*)d_in[14];
    float* out = (float*)d_out;
    const int* src = ei;
    const int* dst = ei + N_EDGES;

    char* p = (char*)d_ws;
    auto alloc = [&](size_t bytes) { char* r = p; p += (bytes + 255) & ~(size_t)255; return r; };
    float* xh1      = (float*)alloc((size_t)N_NODES * 128 * 4);
    float* h1       = (float*)alloc((size_t)N_NODES * 128 * 4);
    float* ew1      = (float*)alloc((size_t)N_EDGES * 8 * 4);
    float* a1s      = (float*)alloc((size_t)N_NODES * 8 * 4);
    float* a1d      = (float*)alloc((size_t)N_NODES * 8 * 4);
    float* xh2      = (float*)alloc((size_t)N_NODES * 16 * 4);
    float* a2s      = (float*)alloc((size_t)N_NODES * 4);
    float* a2d      = (float*)alloc((size_t)N_NODES * 4);
    float* ae2      = (float*)alloc((size_t)N_EDGES * 4);
    int*   eid      = (int*)alloc((size_t)N_EDGES * 4);
    int*   count    = (int*)alloc((size_t)N_NODES * 4);
    int*   cursor   = (int*)alloc((size_t)N_NODES * 4);   // contiguous after count
    int*   offs     = (int*)alloc((size_t)(N_NODES + 1) * 4);
    int*   partials = (int*)alloc(1024 * 4);
    float* M1       = (float*)alloc(128 * 4);
    float* M2       = (float*)alloc(64 * 4);
    if ((size_t)(p - (char*)d_ws) > ws_size) return;  // workspace too small — fail visibly

    const int nb_scan = (N_NODES + 255) / 256;  // 391

    hipMemsetAsync(count, 0, (size_t)2 * N_NODES * 4 + 256, stream);  // count + cursor
    k_pre<<<1, 192, 0, stream>>>(We1, attE1, We2, attE2, M1, M2);
    k_gemm1<<<N_NODES / 16, 256, 0, stream>>>(x, W1, attS1, attD1, xh1, a1s, a1d);
    k_hist<<<(N_EDGES + 255) / 256, 256, 0, stream>>>(dst, count);
    k_scan1<<<nb_scan, 256, 0, stream>>>(count, offs, partials);
    k_scan2<<<1, 512, 0, stream>>>(partials, nb_scan);
    k_scan3<<<nb_scan, 256, 0, stream>>>(offs, partials);
    k_attn<<<N_EDGES / 256, 256, 0, stream>>>(src, dst, ea, M1, M2, a1s, a1d, ew1, ae2);
    k_scatter<<<N_EDGES / 256, 256, 0, stream>>>(dst, offs, cursor, eid);
    k_agg1<<<N_NODES, 128, 0, stream>>>(eid, src, ew1, xh1, offs, count, b1, h1);
    k_gemm2<<<N_NODES / 16, 256, 0, stream>>>(h1, W2, attS2, attD2, xh2, a2s, a2d);
    k_agg2<<<N_NODES, 64, 0, stream>>>(eid, src, ae2, a2s, a2d, xh2, offs, count, b2, out);
}

// Round 3
// 779.774 us; speedup vs baseline: 1.0917x; 1.0917x over previous
//
#include <hip/hip_runtime.h>
#include <hip/hip_bf16.h>

#define N_NODES 100000
#define N_EDGES 1600000
#define NEG_SLOPE 0.2f

// ---------------- precompute M1[16][8], M2[16] ----------------
__global__ void k_pre(const float* __restrict__ We1, const float* __restrict__ attE1,
                      const float* __restrict__ We2, const float* __restrict__ attE2,
                      float* __restrict__ M1, float* __restrict__ M2) {
    int t = threadIdx.x;
    if (t < 128) {
        int d = t >> 3, h = t & 7;
        float s = 0.f;
        for (int c = 0; c < 16; ++c) s += We1[d * 128 + h * 16 + c] * attE1[h * 16 + c];
        M1[d * 8 + h] = s;   // layout [d][h]
    } else if (t < 144) {
        int d = t - 128;
        float s = 0.f;
        for (int c = 0; c < 16; ++c) s += We2[d * 16 + c] * attE2[c];
        M2[d] = s;
    }
}

// ---------------- GEMM1: xh1 = x @ W1, plus a1s/a1d ----------------
__global__ __launch_bounds__(256) void k_gemm1(
    const float* __restrict__ x, const float* __restrict__ W1,
    const float* __restrict__ attS, const float* __restrict__ attD,
    float* __restrict__ xh1, float* __restrict__ a1s, float* __restrict__ a1d) {
    __shared__ float Ws[128 * 128];
    int tid = threadIdx.x;
    for (int i = tid * 4; i < 16384; i += 1024)
        *(float4*)(Ws + i) = *(const float4*)(W1 + i);
    __syncthreads();
    int tx = tid & 31, ty = tid >> 5;
    int r0 = blockIdx.x * 16 + ty;     // and r0+8
    int c0 = tx * 4;
    const float* xr0 = x + (size_t)r0 * 128;
    const float* xr1 = xr0 + 8 * 128;
    float acc0[4] = {0.f, 0.f, 0.f, 0.f};
    float acc1[4] = {0.f, 0.f, 0.f, 0.f};
    for (int k = 0; k < 128; k += 4) {
        float4 xa4 = *(const float4*)(xr0 + k);
        float4 xb4 = *(const float4*)(xr1 + k);
        float xa[4] = {xa4.x, xa4.y, xa4.z, xa4.w};
        float xb[4] = {xb4.x, xb4.y, xb4.z, xb4.w};
#pragma unroll
        for (int j = 0; j < 4; ++j) {
            float4 w = *(const float4*)(Ws + (k + j) * 128 + c0);
            acc0[0] += xa[j] * w.x; acc0[1] += xa[j] * w.y;
            acc0[2] += xa[j] * w.z; acc0[3] += xa[j] * w.w;
            acc1[0] += xb[j] * w.x; acc1[1] += xb[j] * w.y;
            acc1[2] += xb[j] * w.z; acc1[3] += xb[j] * w.w;
        }
    }
    float4 o0 = {acc0[0], acc0[1], acc0[2], acc0[3]};
    float4 o1 = {acc1[0], acc1[1], acc1[2], acc1[3]};
    *(float4*)(xh1 + (size_t)r0 * 128 + c0) = o0;
    *(float4*)(xh1 + (size_t)(r0 + 8) * 128 + c0) = o1;
    int h = tx >> 2;
    int cc = (tx & 3) * 4;
    float ps0 = 0.f, pd0 = 0.f, ps1 = 0.f, pd1 = 0.f;
#pragma unroll
    for (int j = 0; j < 4; ++j) {
        float aS = attS[h * 16 + cc + j];
        float aD = attD[h * 16 + cc + j];
        ps0 += acc0[j] * aS; pd0 += acc0[j] * aD;
        ps1 += acc1[j] * aS; pd1 += acc1[j] * aD;
    }
    ps0 += __shfl_xor(ps0, 1); ps0 += __shfl_xor(ps0, 2);
    pd0 += __shfl_xor(pd0, 1); pd0 += __shfl_xor(pd0, 2);
    ps1 += __shfl_xor(ps1, 1); ps1 += __shfl_xor(ps1, 2);
    pd1 += __shfl_xor(pd1, 1); pd1 += __shfl_xor(pd1, 2);
    if ((tx & 3) == 0) {
        a1s[(size_t)r0 * 8 + h] = ps0;       a1d[(size_t)r0 * 8 + h] = pd0;
        a1s[(size_t)(r0 + 8) * 8 + h] = ps1; a1d[(size_t)(r0 + 8) * 8 + h] = pd1;
    }
}

// ---------------- CSR build ----------------
__global__ void k_hist(const int* __restrict__ dst, int* __restrict__ count) {
    int i = blockIdx.x * blockDim.x + threadIdx.x;
    if (i < N_EDGES) atomicAdd(&count[dst[i]], 1);
}

__global__ __launch_bounds__(256) void k_scan1(const int* __restrict__ count,
                                               int* __restrict__ offs, int* __restrict__ partials) {
    __shared__ int s[256];
    int t = threadIdx.x;
    int i = blockIdx.x * 256 + t;
    int v = (i < N_NODES) ? count[i] : 0;
    s[t] = v; __syncthreads();
    for (int off = 1; off < 256; off <<= 1) {
        int add = (t >= off) ? s[t - off] : 0;
        __syncthreads();
        s[t] += add; __syncthreads();
    }
    if (i < N_NODES) offs[i] = s[t] - v;
    if (t == 255) partials[blockIdx.x] = s[255];
}

__global__ __launch_bounds__(512) void k_scan2(int* __restrict__ partials, int nb) {
    __shared__ int s[512];
    int t = threadIdx.x;
    int v = (t < nb) ? partials[t] : 0;
    s[t] = v; __syncthreads();
    for (int off = 1; off < 512; off <<= 1) {
        int add = (t >= off) ? s[t - off] : 0;
        __syncthreads();
        s[t] += add; __syncthreads();
    }
    if (t < nb) partials[t] = s[t] - v;
}

__global__ void k_scan3(int* __restrict__ offs, const int* __restrict__ partials) {
    int i = blockIdx.x * 256 + threadIdx.x;
    if (i < N_NODES) offs[i] += partials[blockIdx.x];
}

// ---------------- k_attn: edge-order streaming, fully coalesced outputs ----------------
__global__ __launch_bounds__(256) void k_attn(
    const int* __restrict__ src, const int* __restrict__ dst,
    const float* __restrict__ ea, const float* __restrict__ M1, const float* __restrict__ M2,
    const float* __restrict__ a1s, const float* __restrict__ a1d,
    float* __restrict__ ew1, float2* __restrict__ as2) {
    __shared__ float M1s[128], M2s[16];
    int t = threadIdx.x;
    if (t < 128) M1s[t] = M1[t];
    if (t >= 128 && t < 144) M2s[t - 128] = M2[t - 128];
    __syncthreads();
    int e = blockIdx.x * 256 + t;
    int s = src[e], d = dst[e];
    float eav[16];
#pragma unroll
    for (int q = 0; q < 4; ++q) {
        float4 v = *(const float4*)(ea + (size_t)e * 16 + q * 4);
        eav[q * 4] = v.x; eav[q * 4 + 1] = v.y; eav[q * 4 + 2] = v.z; eav[q * 4 + 3] = v.w;
    }
    float ae1[8];
#pragma unroll
    for (int h = 0; h < 8; ++h) ae1[h] = 0.f;
#pragma unroll
    for (int dd = 0; dd < 16; ++dd) {
#pragma unroll
        for (int h = 0; h < 8; ++h) ae1[h] += eav[dd] * M1s[dd * 8 + h];
    }
    float aes = 0.f;
#pragma unroll
    for (int dd = 0; dd < 16; ++dd) aes += eav[dd] * M2s[dd];
    float4 s0 = *(const float4*)(a1s + (size_t)s * 8);
    float4 s1 = *(const float4*)(a1s + (size_t)s * 8 + 4);
    float4 d0 = *(const float4*)(a1d + (size_t)d * 8);
    float4 d1 = *(const float4*)(a1d + (size_t)d * 8 + 4);
    float as_[8] = {s0.x, s0.y, s0.z, s0.w, s1.x, s1.y, s1.z, s1.w};
    float ad_[8] = {d0.x, d0.y, d0.z, d0.w, d1.x, d1.y, d1.z, d1.w};
    float ew[8];
#pragma unroll
    for (int h = 0; h < 8; ++h) {
        float v = as_[h] + ad_[h] + ae1[h];
        v = v > 0.f ? v : NEG_SLOPE * v;
        ew[h] = __expf(v);
    }
    float4 w0 = {ew[0], ew[1], ew[2], ew[3]};
    float4 w1 = {ew[4], ew[5], ew[6], ew[7]};
    *(float4*)(ew1 + (size_t)e * 8) = w0;
    *(float4*)(ew1 + (size_t)e * 8 + 4) = w1;
    float2 m; m.x = aes; m.y = __int_as_float(s);
    as2[e] = m;
}

// ---------------- k_scatter: 4-byte permutation scatter only ----------------
__global__ __launch_bounds__(256) void k_scatter(
    const int* __restrict__ dst, const int* __restrict__ offs,
    int* __restrict__ cursor, int* __restrict__ eid) {
    int e = blockIdx.x * 256 + threadIdx.x;
    int d = dst[e];
    int p = offs[d] + atomicAdd(&cursor[d], 1);
    eid[p] = e;
}

// ---------------- k_reorder: gather once into CSR-contiguous arrays ----------------
__global__ __launch_bounds__(256) void k_reorder(
    const int* __restrict__ eid, const float* __restrict__ ew1, const float2* __restrict__ as2,
    float* __restrict__ ew1c, float* __restrict__ ae2c, int* __restrict__ srcc) {
    int p = blockIdx.x * 256 + threadIdx.x;
    int e = eid[p];
    float4 w0 = *(const float4*)(ew1 + (size_t)e * 8);
    float4 w1 = *(const float4*)(ew1 + (size_t)e * 8 + 4);
    float2 m = as2[e];
    *(float4*)(ew1c + (size_t)p * 8) = w0;
    *(float4*)(ew1c + (size_t)p * 8 + 4) = w1;
    ae2c[p] = m.x;
    srcc[p] = __float_as_int(m.y);
}

// ---------------- layer-1 aggregation: block per node, float4 gathers ----------------
// 128 threads: j = t&31 (float4 column group, head h = j>>2), k = t>>5 (4 edge slots)
__global__ __launch_bounds__(128) void k_agg1(
    const int* __restrict__ srcc, const float* __restrict__ ew1c,
    const float* __restrict__ xh1, const int* __restrict__ offs, const int* __restrict__ count,
    const float* __restrict__ b1, float* __restrict__ h1) {
    __shared__ float4 racc[32];
    __shared__ float rw[32];
    int n = blockIdx.x;
    int t = threadIdx.x;
    int j = t & 31, k = t >> 5;
    int start = offs[n], deg = count[n];
    float4 acc = {0.f, 0.f, 0.f, 0.f};
    float wsum = 0.f;
    int i = k;
    int s = 0; float w = 0.f;
    if (i < deg) {
        int p = start + i;
        s = srcc[p];
        w = ew1c[(size_t)p * 8 + (j >> 2)];
    }
    while (i < deg) {
        int ni = i + 4;
        int ns = 0; float nw = 0.f;
        if (ni < deg) {                       // prefetch next edge's src/weight
            int np = start + ni;
            ns = srcc[np];
            nw = ew1c[(size_t)np * 8 + (j >> 2)];
        }
        float4 xv = *(const float4*)(xh1 + (size_t)s * 128 + j * 4);
        acc.x += w * xv.x; acc.y += w * xv.y; acc.z += w * xv.z; acc.w += w * xv.w;
        wsum += w;
        i = ni; s = ns; w = nw;
    }
    // combine k within wave (lanes t, t^32)
    acc.x += __shfl_xor(acc.x, 32); acc.y += __shfl_xor(acc.y, 32);
    acc.z += __shfl_xor(acc.z, 32); acc.w += __shfl_xor(acc.w, 32);
    wsum += __shfl_xor(wsum, 32);
    if (t >= 64 && t < 96) { racc[j] = acc; rw[j] = wsum; }
    __syncthreads();
    if (t < 32) {
        float4 o = racc[j];
        acc.x += o.x; acc.y += o.y; acc.z += o.z; acc.w += o.w;
        wsum += rw[j];
        float inv = 1.f / (wsum + 1e-16f);
        float4 b = *(const float4*)(b1 + j * 4);
        float4 r;
        r.x = acc.x * inv + b.x; r.y = acc.y * inv + b.y;
        r.z = acc.z * inv + b.z; r.w = acc.w * inv + b.w;
        r.x = r.x > 0.f ? r.x : __expf(r.x) - 1.f;
        r.y = r.y > 0.f ? r.y : __expf(r.y) - 1.f;
        r.z = r.z > 0.f ? r.z : __expf(r.z) - 1.f;
        r.w = r.w > 0.f ? r.w : __expf(r.w) - 1.f;
        *(float4*)(h1 + (size_t)n * 128 + j * 4) = r;
    }
}

// ---------------- GEMM2: xh2 = h1 @ W2, plus a2s/a2d ----------------
__global__ __launch_bounds__(256) void k_gemm2(
    const float* __restrict__ h1, const float* __restrict__ W2,
    const float* __restrict__ attS, const float* __restrict__ attD,
    float* __restrict__ xh2, float* __restrict__ a2s, float* __restrict__ a2d) {
    __shared__ float W2s[128 * 16];
    __shared__ float hs[16 * 132];   // +4 pad to break bank conflicts
    int t = threadIdx.x;
    for (int i = t * 4; i < 2048; i += 1024)
        *(float4*)(W2s + i) = *(const float4*)(W2 + i);
    size_t base = (size_t)blockIdx.x * 16 * 128;
    for (int i = t * 4; i < 2048; i += 1024) {
        float4 v = *(const float4*)(h1 + base + i);
        int r = i >> 7, k = i & 127;
        float* dstp = hs + r * 132 + k;
        dstp[0] = v.x; dstp[1] = v.y; dstp[2] = v.z; dstp[3] = v.w;
    }
    __syncthreads();
    int r = t >> 4, c = t & 15;
    float acc = 0.f;
#pragma unroll 4
    for (int k = 0; k < 128; ++k) acc += hs[r * 132 + k] * W2s[k * 16 + c];
    int row = blockIdx.x * 16 + r;
    xh2[(size_t)row * 16 + c] = acc;
    float ps = acc * attS[c], pd = acc * attD[c];
#pragma unroll
    for (int m = 1; m < 16; m <<= 1) { ps += __shfl_xor(ps, m); pd += __shfl_xor(pd, m); }
    if (c == 0) { a2s[row] = ps; a2d[row] = pd; }
}

// ---------------- layer-2 aggregation + bias + log_softmax ----------------
// 64 threads: l = t&3 (float4 col group), k = t>>2 (16 edge slots)
__global__ __launch_bounds__(64) void k_agg2(
    const int* __restrict__ srcc, const float* __restrict__ ae2c,
    const float* __restrict__ a2s, const float* __restrict__ a2d, const float* __restrict__ xh2,
    const int* __restrict__ offs, const int* __restrict__ count,
    const float* __restrict__ b2, float* __restrict__ out) {
    int n = blockIdx.x;
    int t = threadIdx.x;
    int l = t & 3, k = t >> 2;
    int start = offs[n], deg = count[n];
    float ad = a2d[n];
    float4 acc = {0.f, 0.f, 0.f, 0.f};
    float wsum = 0.f;
    for (int i = k; i < deg; i += 16) {
        int p = start + i;
        int s = srcc[p];
        float lg = a2s[s] + ad + ae2c[p];
        lg = lg > 0.f ? lg : NEG_SLOPE * lg;
        float w = __expf(lg);
        float4 xv = *(const float4*)(xh2 + (size_t)s * 16 + l * 4);
        acc.x += w * xv.x; acc.y += w * xv.y; acc.z += w * xv.z; acc.w += w * xv.w;
        wsum += w;
    }
#pragma unroll
    for (int m = 4; m < 64; m <<= 1) {
        acc.x += __shfl_xor(acc.x, m); acc.y += __shfl_xor(acc.y, m);
        acc.z += __shfl_xor(acc.z, m); acc.w += __shfl_xor(acc.w, m);
        wsum += __shfl_xor(wsum, m);
    }
    float inv = 1.f / (wsum + 1e-16f);
    float4 b = *(const float4*)(b2 + l * 4);
    float4 lo;
    lo.x = acc.x * inv + b.x; lo.y = acc.y * inv + b.y;
    lo.z = acc.z * inv + b.z; lo.w = acc.w * inv + b.w;
    float mx = fmaxf(fmaxf(lo.x, lo.y), fmaxf(lo.z, lo.w));
    mx = fmaxf(mx, __shfl_xor(mx, 1)); mx = fmaxf(mx, __shfl_xor(mx, 2));
    float ex = __expf(lo.x - mx) + __expf(lo.y - mx) + __expf(lo.z - mx) + __expf(lo.w - mx);
    ex += __shfl_xor(ex, 1); ex += __shfl_xor(ex, 2);
    float ls = mx + __logf(ex);
    if (t < 4) {
        float4 r = {lo.x - ls, lo.y - ls, lo.z - ls, lo.w - ls};
        *(float4*)(out + (size_t)n * 16 + l * 4) = r;
    }
}

extern "C" void kernel_launch(void* const* d_in, const int* in_sizes, int n_in,
                              void* d_out, int out_size, void* d_ws, size_t ws_size,
                              hipStream_t stream) {
    const float* x     = (const float*)d_in[0];
    const int*   ei    = (const int*)d_in[1];
    const float* ea    = (const float*)d_in[2];
    const float* W1    = (const float*)d_in[3];
    const float* attS1 = (const float*)d_in[4];
    const float* attD1 = (const float*)d_in[5];
    const float* We1   = (const float*)d_in[6];
    const float* attE1 = (const float*)d_in[7];
    const float* b1    = (const float*)d_in[8];
    const float* W2    = (const float*)d_in[9];
    const float* attS2 = (const float*)d_in[10];
    const float* attD2 = (const float*)d_in[11];
    const float* We2   = (const float*)d_in[12];
    const float* attE2 = (const float*)d_in[13];
    const float* b2    = (const float*)d_in[14];
    float* out = (float*)d_out;
    const int* src = ei;
    const int* dst = ei + N_EDGES;

    char* p = (char*)d_ws;
    auto alloc = [&](size_t bytes) { char* r = p; p += (bytes + 255) & ~(size_t)255; return r; };
    // Region A: xh1 (gemm1 -> agg1)
    float* xh1  = (float*)alloc((size_t)N_NODES * 128 * 4);          // 51.2 MB
    // Region B: ew1 (attn -> reorder), later h1 (agg1 -> gemm2)
    float* ew1  = (float*)alloc((size_t)N_EDGES * 8 * 4);            // 51.2 MB
    float* h1   = ew1;                                               // alias: ew1 dead after reorder
    // Region C: as2 (attn -> reorder), later xh2+a2s+a2d (gemm2 -> agg2)
    char*  regC = alloc((size_t)N_EDGES * 8);                        // 12.8 MB
    float2* as2 = (float2*)regC;
    float* xh2  = (float*)regC;                                      // 6.4 MB
    float* a2s  = (float*)(regC + (size_t)N_NODES * 16 * 4);         // 0.4 MB
    float* a2d  = a2s + N_NODES;                                     // 0.4 MB
    // Region D: CSR-ordered edge data
    float* ew1c = (float*)alloc((size_t)N_EDGES * 8 * 4);            // 51.2 MB
    float* ae2c = (float*)alloc((size_t)N_EDGES * 4);                // 6.4 MB
    int*   srcc = (int*)alloc((size_t)N_EDGES * 4);                  // 6.4 MB
    // Region F/G: small buffers
    float* a1s      = (float*)alloc((size_t)N_NODES * 8 * 4);
    float* a1d      = (float*)alloc((size_t)N_NODES * 8 * 4);
    int*   eid      = (int*)alloc((size_t)N_EDGES * 4);
    int*   count    = (int*)alloc((size_t)N_NODES * 4);
    int*   cursor   = (int*)alloc((size_t)N_NODES * 4);   // contiguous after count
    int*   offs     = (int*)alloc((size_t)(N_NODES + 1) * 4);
    int*   partials = (int*)alloc(1024 * 4);
    float* M1       = (float*)alloc(128 * 4);
    float* M2       = (float*)alloc(64 * 4);
    if ((size_t)(p - (char*)d_ws) > ws_size) return;  // workspace too small — fail visibly

    const int nb_scan = (N_NODES + 255) / 256;  // 391

    hipMemsetAsync(count, 0, (size_t)2 * N_NODES * 4 + 256, stream);  // count + cursor
    k_pre<<<1, 192, 0, stream>>>(We1, attE1, We2, attE2, M1, M2);
    k_gemm1<<<N_NODES / 16, 256, 0, stream>>>(x, W1, attS1, attD1, xh1, a1s, a1d);
    k_hist<<<(N_EDGES + 255) / 256, 256, 0, stream>>>(dst, count);
    k_scan1<<<nb_scan, 256, 0, stream>>>(count, offs, partials);
    k_scan2<<<1, 512, 0, stream>>>(partials, nb_scan);
    k_scan3<<<nb_scan, 256, 0, stream>>>(offs, partials);
    k_attn<<<N_EDGES / 256, 256, 0, stream>>>(src, dst, ea, M1, M2, a1s, a1d, ew1, as2);
    k_scatter<<<N_EDGES / 256, 256, 0, stream>>>(dst, offs, cursor, eid);
    k_reorder<<<N_EDGES / 256, 256, 0, stream>>>(eid, ew1, as2, ew1c, ae2c, srcc);
    k_agg1<<<N_NODES, 128, 0, stream>>>(srcc, ew1c, xh1, offs, count, b1, h1);
    k_gemm2<<<N_NODES / 16, 256, 0, stream>>>(h1, W2, attS2, attD2, xh2, a2s, a2d);
    k_agg2<<<N_NODES, 64, 0, stream>>>(srcc, ae2c, a2s, a2d, xh2, offs, count, b2, out);
}

// Round 4
// 678.702 us; speedup vs baseline: 1.2543x; 1.1489x over previous
//
#include <hip/hip_runtime.h>
#include <hip/hip_bf16.h>

#define N_NODES 100000
#define N_EDGES 1600000
#define NEG_SLOPE 0.2f
#define LDS_STRIDE 132

typedef __attribute__((ext_vector_type(8))) short short8;
typedef __attribute__((ext_vector_type(4))) short short4v;
typedef __attribute__((ext_vector_type(4))) float floatx4;

__device__ inline short f2bf(float f) {
    __hip_bfloat16 h = __float2bfloat16(f);
    return *reinterpret_cast<short*>(&h);
}
__device__ inline float bf2f(unsigned short u) {
    union { unsigned int i; float f; } z; z.i = ((unsigned int)u) << 16; return z.f;
}

// ---------------- precompute M1[16][8], M2[16] ----------------
__global__ void k_pre(const float* __restrict__ We1, const float* __restrict__ attE1,
                      const float* __restrict__ We2, const float* __restrict__ attE2,
                      float* __restrict__ M1, float* __restrict__ M2) {
    int t = threadIdx.x;
    if (t < 128) {
        int d = t >> 3, h = t & 7;
        float s = 0.f;
        for (int c = 0; c < 16; ++c) s += We1[d * 128 + h * 16 + c] * attE1[h * 16 + c];
        M1[d * 8 + h] = s;   // layout [d][h]
    } else if (t < 144) {
        int d = t - 128;
        float s = 0.f;
        for (int c = 0; c < 16; ++c) s += We2[d * 16 + c] * attE2[c];
        M2[d] = s;
    }
}

// ---------------- GEMM1 via bf16 MFMA: xh1b (bf16) + a1s/a1d (fp32) ----------------
// block 256 = 4 waves; wave w computes rows [blk*64 + w*16, +16) x all 128 cols.
// A-frag: lane l: A[m=l&15][k=(l>>4)*8+j]; B-frag: B[k=(l>>4)*8+j][n=l&15];
// C/D: c[r] = C[(l>>4)*4+r][l&15]   (guide §3, m89/m91-verified mapping)
__global__ __launch_bounds__(256) void k_gemm1(
    const float* __restrict__ x, const float* __restrict__ W1,
    const float* __restrict__ attS, const float* __restrict__ attD,
    __hip_bfloat16* __restrict__ xh1b, float* __restrict__ a1s, float* __restrict__ a1d) {
    __shared__ short lds[128 * LDS_STRIDE];   // W1^T bf16 [n][k], later reused for out-tile
    int t = threadIdx.x;
    for (int i = t * 4; i < 16384; i += 1024) {
        float4 v = *(const float4*)(W1 + i);
        int k = i >> 7, n = i & 127;
        lds[(n + 0) * LDS_STRIDE + k] = f2bf(v.x);
        lds[(n + 1) * LDS_STRIDE + k] = f2bf(v.y);
        lds[(n + 2) * LDS_STRIDE + k] = f2bf(v.z);
        lds[(n + 3) * LDS_STRIDE + k] = f2bf(v.w);
    }
    __syncthreads();
    int w = t >> 6, l = t & 63;
    int q = l >> 4, m = l & 15;
    int row = blockIdx.x * 64 + w * 16 + m;
    int rowc = row < N_NODES ? row : 0;
    floatx4 acc[8];
#pragma unroll
    for (int nt = 0; nt < 8; ++nt) acc[nt] = (floatx4){0.f, 0.f, 0.f, 0.f};
#pragma unroll
    for (int KK = 0; KK < 4; ++KK) {
        int k0 = KK * 32 + q * 8;
        float4 alo = *(const float4*)(x + (size_t)rowc * 128 + k0);
        float4 ahi = *(const float4*)(x + (size_t)rowc * 128 + k0 + 4);
        short8 a = {f2bf(alo.x), f2bf(alo.y), f2bf(alo.z), f2bf(alo.w),
                    f2bf(ahi.x), f2bf(ahi.y), f2bf(ahi.z), f2bf(ahi.w)};
#pragma unroll
        for (int nt = 0; nt < 8; ++nt) {
            const short* bp = &lds[(nt * 16 + m) * LDS_STRIDE + k0];
            short4v blo = *(const short4v*)bp;
            short4v bhi = *(const short4v*)(bp + 4);
            short8 b = {blo.x, blo.y, blo.z, blo.w, bhi.x, bhi.y, bhi.z, bhi.w};
            acc[nt] = __builtin_amdgcn_mfma_f32_16x16x32_bf16(a, b, acc[nt], 0, 0, 0);
        }
    }
    // per-head attention dots from exact fp32 accumulators; head == n-tile index
    int rb = blockIdx.x * 64 + w * 16 + q * 4;
#pragma unroll
    for (int nt = 0; nt < 8; ++nt) {
        float aS = attS[nt * 16 + m], aD = attD[nt * 16 + m];
        float p0 = acc[nt][0] * aS, p1 = acc[nt][1] * aS, p2 = acc[nt][2] * aS, p3 = acc[nt][3] * aS;
        float d0 = acc[nt][0] * aD, d1 = acc[nt][1] * aD, d2 = acc[nt][2] * aD, d3 = acc[nt][3] * aD;
        for (int dd = 1; dd < 16; dd <<= 1) {
            p0 += __shfl_xor(p0, dd); p1 += __shfl_xor(p1, dd);
            p2 += __shfl_xor(p2, dd); p3 += __shfl_xor(p3, dd);
            d0 += __shfl_xor(d0, dd); d1 += __shfl_xor(d1, dd);
            d2 += __shfl_xor(d2, dd); d3 += __shfl_xor(d3, dd);
        }
        if (m == 0) {
            if (rb + 0 < N_NODES) { a1s[(size_t)(rb+0)*8+nt] = p0; a1d[(size_t)(rb+0)*8+nt] = d0; }
            if (rb + 1 < N_NODES) { a1s[(size_t)(rb+1)*8+nt] = p1; a1d[(size_t)(rb+1)*8+nt] = d1; }
            if (rb + 2 < N_NODES) { a1s[(size_t)(rb+2)*8+nt] = p2; a1d[(size_t)(rb+2)*8+nt] = d2; }
            if (rb + 3 < N_NODES) { a1s[(size_t)(rb+3)*8+nt] = p3; a1d[(size_t)(rb+3)*8+nt] = d3; }
        }
    }
    // stage C-tile to LDS (bf16) then coalesced global write
    __syncthreads();
#pragma unroll
    for (int nt = 0; nt < 8; ++nt) {
#pragma unroll
        for (int r = 0; r < 4; ++r)
            lds[(w * 16 + q * 4 + r) * LDS_STRIDE + nt * 16 + m] = f2bf(acc[nt][r]);
    }
    __syncthreads();
    int r2 = t >> 2, c2 = (t & 3) * 32;
    int gr = blockIdx.x * 64 + r2;
    if (gr < N_NODES) {
        short* gp = (short*)(xh1b + (size_t)gr * 128 + c2);
#pragma unroll
        for (int i = 0; i < 8; ++i)
            *(short4v*)(gp + i * 4) = *(const short4v*)&lds[r2 * LDS_STRIDE + c2 + i * 4];
    }
}

// ---------------- CSR build ----------------
__global__ void k_hist(const int* __restrict__ dst, int* __restrict__ count) {
    int i = blockIdx.x * blockDim.x + threadIdx.x;
    if (i < N_EDGES) atomicAdd(&count[dst[i]], 1);
}

__global__ __launch_bounds__(256) void k_scan1(const int* __restrict__ count,
                                               int* __restrict__ offs, int* __restrict__ partials) {
    __shared__ int s[256];
    int t = threadIdx.x;
    int i = blockIdx.x * 256 + t;
    int v = (i < N_NODES) ? count[i] : 0;
    s[t] = v; __syncthreads();
    for (int off = 1; off < 256; off <<= 1) {
        int add = (t >= off) ? s[t - off] : 0;
        __syncthreads();
        s[t] += add; __syncthreads();
    }
    if (i < N_NODES) offs[i] = s[t] - v;
    if (t == 255) partials[blockIdx.x] = s[255];
}

__global__ __launch_bounds__(512) void k_scan2(int* __restrict__ partials, int nb) {
    __shared__ int s[512];
    int t = threadIdx.x;
    int v = (t < nb) ? partials[t] : 0;
    s[t] = v; __syncthreads();
    for (int off = 1; off < 512; off <<= 1) {
        int add = (t >= off) ? s[t - off] : 0;
        __syncthreads();
        s[t] += add; __syncthreads();
    }
    if (t < nb) partials[t] = s[t] - v;
}

__global__ void k_scan3(int* __restrict__ offs, const int* __restrict__ partials) {
    int i = blockIdx.x * 256 + threadIdx.x;
    if (i < N_NODES) offs[i] += partials[blockIdx.x];
}

// ---------------- k_scatter: 4-byte permutation scatter only ----------------
__global__ __launch_bounds__(256) void k_scatter(
    const int* __restrict__ dst, const int* __restrict__ offs,
    int* __restrict__ cursor, int* __restrict__ eid) {
    int e = blockIdx.x * 256 + threadIdx.x;
    int d = dst[e];
    int p = offs[d] + atomicAdd(&cursor[d], 1);
    eid[p] = e;
}

// ---------------- k_attn: CSR-order gather-in, coalesced-out ----------------
__global__ __launch_bounds__(256) void k_attn(
    const int* __restrict__ eid, const int* __restrict__ src, const int* __restrict__ dst,
    const float* __restrict__ ea, const float* __restrict__ M1, const float* __restrict__ M2,
    const float* __restrict__ a1s, const float* __restrict__ a1d,
    float* __restrict__ ew1c, float* __restrict__ ae2c, int* __restrict__ srcc) {
    __shared__ float M1s[128], M2s[16];
    int t = threadIdx.x;
    if (t < 128) M1s[t] = M1[t];
    if (t >= 128 && t < 144) M2s[t - 128] = M2[t - 128];
    __syncthreads();
    int p = blockIdx.x * 256 + t;
    int e = eid[p];
    int s = src[e], d = dst[e];
    float eav[16];
#pragma unroll
    for (int qq = 0; qq < 4; ++qq) {
        float4 v = *(const float4*)(ea + (size_t)e * 16 + qq * 4);
        eav[qq * 4] = v.x; eav[qq * 4 + 1] = v.y; eav[qq * 4 + 2] = v.z; eav[qq * 4 + 3] = v.w;
    }
    float ae1[8];
#pragma unroll
    for (int h = 0; h < 8; ++h) ae1[h] = 0.f;
#pragma unroll
    for (int dd = 0; dd < 16; ++dd) {
#pragma unroll
        for (int h = 0; h < 8; ++h) ae1[h] += eav[dd] * M1s[dd * 8 + h];
    }
    float aes = 0.f;
#pragma unroll
    for (int dd = 0; dd < 16; ++dd) aes += eav[dd] * M2s[dd];
    float4 s0 = *(const float4*)(a1s + (size_t)s * 8);
    float4 s1 = *(const float4*)(a1s + (size_t)s * 8 + 4);
    float4 d0 = *(const float4*)(a1d + (size_t)d * 8);
    float4 d1 = *(const float4*)(a1d + (size_t)d * 8 + 4);
    float as_[8] = {s0.x, s0.y, s0.z, s0.w, s1.x, s1.y, s1.z, s1.w};
    float ad_[8] = {d0.x, d0.y, d0.z, d0.w, d1.x, d1.y, d1.z, d1.w};
    float ew[8];
#pragma unroll
    for (int h = 0; h < 8; ++h) {
        float v = as_[h] + ad_[h] + ae1[h];
        v = v > 0.f ? v : NEG_SLOPE * v;
        ew[h] = __expf(v);
    }
    float4 w0 = {ew[0], ew[1], ew[2], ew[3]};
    float4 w1 = {ew[4], ew[5], ew[6], ew[7]};
    *(float4*)(ew1c + (size_t)p * 8) = w0;
    *(float4*)(ew1c + (size_t)p * 8 + 4) = w1;
    ae2c[p] = aes;
    srcc[p] = s;
}

// ---------------- layer-1 aggregation: bf16 row gathers ----------------
// 128 threads: j = t&31 (4-col group, head h=j>>2), k = t>>5 (4 edge slots)
__global__ __launch_bounds__(128) void k_agg1(
    const int* __restrict__ srcc, const float* __restrict__ ew1c,
    const __hip_bfloat16* __restrict__ xh1b, const int* __restrict__ offs,
    const int* __restrict__ count, const float* __restrict__ b1, float* __restrict__ h1) {
    __shared__ float4 racc[32];
    __shared__ float rw[32];
    int n = blockIdx.x;
    int t = threadIdx.x;
    int j = t & 31, k = t >> 5;
    int start = offs[n], deg = count[n];
    float4 acc = {0.f, 0.f, 0.f, 0.f};
    float wsum = 0.f;
    int i = k;
    int s = 0; float w = 0.f;
    if (i < deg) {
        int p = start + i;
        s = srcc[p];
        w = ew1c[(size_t)p * 8 + (j >> 2)];
    }
    while (i < deg) {
        int ni = i + 4;
        int ns = 0; float nw = 0.f;
        if (ni < deg) {                       // prefetch next edge's src/weight
            int np = start + ni;
            ns = srcc[np];
            nw = ew1c[(size_t)np * 8 + (j >> 2)];
        }
        uint2 xv = *(const uint2*)((const char*)xh1b + (size_t)s * 256 + j * 8);
        float x0 = bf2f((unsigned short)(xv.x & 0xffff));
        float x1 = bf2f((unsigned short)(xv.x >> 16));
        float x2 = bf2f((unsigned short)(xv.y & 0xffff));
        float x3 = bf2f((unsigned short)(xv.y >> 16));
        acc.x += w * x0; acc.y += w * x1; acc.z += w * x2; acc.w += w * x3;
        wsum += w;
        i = ni; s = ns; w = nw;
    }
    acc.x += __shfl_xor(acc.x, 32); acc.y += __shfl_xor(acc.y, 32);
    acc.z += __shfl_xor(acc.z, 32); acc.w += __shfl_xor(acc.w, 32);
    wsum += __shfl_xor(wsum, 32);
    if (t >= 64 && t < 96) { racc[j] = acc; rw[j] = wsum; }
    __syncthreads();
    if (t < 32) {
        float4 o = racc[j];
        acc.x += o.x; acc.y += o.y; acc.z += o.z; acc.w += o.w;
        wsum += rw[j];
        float inv = 1.f / (wsum + 1e-16f);
        float4 b = *(const float4*)(b1 + j * 4);
        float4 r;
        r.x = acc.x * inv + b.x; r.y = acc.y * inv + b.y;
        r.z = acc.z * inv + b.z; r.w = acc.w * inv + b.w;
        r.x = r.x > 0.f ? r.x : __expf(r.x) - 1.f;
        r.y = r.y > 0.f ? r.y : __expf(r.y) - 1.f;
        r.z = r.z > 0.f ? r.z : __expf(r.z) - 1.f;
        r.w = r.w > 0.f ? r.w : __expf(r.w) - 1.f;
        *(float4*)(h1 + (size_t)n * 128 + j * 4) = r;
    }
}

// ---------------- GEMM2: xh2 = h1 @ W2, plus a2s/a2d ----------------
__global__ __launch_bounds__(256) void k_gemm2(
    const float* __restrict__ h1, const float* __restrict__ W2,
    const float* __restrict__ attS, const float* __restrict__ attD,
    float* __restrict__ xh2, float* __restrict__ a2s, float* __restrict__ a2d) {
    __shared__ float W2s[128 * 16];
    __shared__ float hs[16 * 132];   // +4 pad to break bank conflicts
    int t = threadIdx.x;
    for (int i = t * 4; i < 2048; i += 1024)
        *(float4*)(W2s + i) = *(const float4*)(W2 + i);
    size_t base = (size_t)blockIdx.x * 16 * 128;
    for (int i = t * 4; i < 2048; i += 1024) {
        float4 v = *(const float4*)(h1 + base + i);
        int r = i >> 7, k = i & 127;
        float* dstp = hs + r * 132 + k;
        dstp[0] = v.x; dstp[1] = v.y; dstp[2] = v.z; dstp[3] = v.w;
    }
    __syncthreads();
    int r = t >> 4, c = t & 15;
    float acc = 0.f;
#pragma unroll 4
    for (int k = 0; k < 128; ++k) acc += hs[r * 132 + k] * W2s[k * 16 + c];
    int row = blockIdx.x * 16 + r;
    xh2[(size_t)row * 16 + c] = acc;
    float ps = acc * attS[c], pd = acc * attD[c];
#pragma unroll
    for (int m = 1; m < 16; m <<= 1) { ps += __shfl_xor(ps, m); pd += __shfl_xor(pd, m); }
    if (c == 0) { a2s[row] = ps; a2d[row] = pd; }
}

// ---------------- layer-2 aggregation + bias + log_softmax ----------------
__global__ __launch_bounds__(64) void k_agg2(
    const int* __restrict__ srcc, const float* __restrict__ ae2c,
    const float* __restrict__ a2s, const float* __restrict__ a2d, const float* __restrict__ xh2,
    const int* __restrict__ offs, const int* __restrict__ count,
    const float* __restrict__ b2, float* __restrict__ out) {
    int n = blockIdx.x;
    int t = threadIdx.x;
    int l = t & 3, k = t >> 2;
    int start = offs[n], deg = count[n];
    float ad = a2d[n];
    float4 acc = {0.f, 0.f, 0.f, 0.f};
    float wsum = 0.f;
    for (int i = k; i < deg; i += 16) {
        int p = start + i;
        int s = srcc[p];
        float lg = a2s[s] + ad + ae2c[p];
        lg = lg > 0.f ? lg : NEG_SLOPE * lg;
        float w = __expf(lg);
        float4 xv = *(const float4*)(xh2 + (size_t)s * 16 + l * 4);
        acc.x += w * xv.x; acc.y += w * xv.y; acc.z += w * xv.z; acc.w += w * xv.w;
        wsum += w;
    }
#pragma unroll
    for (int m = 4; m < 64; m <<= 1) {
        acc.x += __shfl_xor(acc.x, m); acc.y += __shfl_xor(acc.y, m);
        acc.z += __shfl_xor(acc.z, m); acc.w += __shfl_xor(acc.w, m);
        wsum += __shfl_xor(wsum, m);
    }
    float inv = 1.f / (wsum + 1e-16f);
    float4 b = *(const float4*)(b2 + l * 4);
    float4 lo;
    lo.x = acc.x * inv + b.x; lo.y = acc.y * inv + b.y;
    lo.z = acc.z * inv + b.z; lo.w = acc.w * inv + b.w;
    float mx = fmaxf(fmaxf(lo.x, lo.y), fmaxf(lo.z, lo.w));
    mx = fmaxf(mx, __shfl_xor(mx, 1)); mx = fmaxf(mx, __shfl_xor(mx, 2));
    float ex = __expf(lo.x - mx) + __expf(lo.y - mx) + __expf(lo.z - mx) + __expf(lo.w - mx);
    ex += __shfl_xor(ex, 1); ex += __shfl_xor(ex, 2);
    float ls = mx + __logf(ex);
    if (t < 4) {
        float4 r = {lo.x - ls, lo.y - ls, lo.z - ls, lo.w - ls};
        *(float4*)(out + (size_t)n * 16 + l * 4) = r;
    }
}

extern "C" void kernel_launch(void* const* d_in, const int* in_sizes, int n_in,
                              void* d_out, int out_size, void* d_ws, size_t ws_size,
                              hipStream_t stream) {
    const float* x     = (const float*)d_in[0];
    const int*   ei    = (const int*)d_in[1];
    const float* ea    = (const float*)d_in[2];
    const float* W1    = (const float*)d_in[3];
    const float* attS1 = (const float*)d_in[4];
    const float* attD1 = (const float*)d_in[5];
    const float* We1   = (const float*)d_in[6];
    const float* attE1 = (const float*)d_in[7];
    const float* b1    = (const float*)d_in[8];
    const float* W2    = (const float*)d_in[9];
    const float* attS2 = (const float*)d_in[10];
    const float* attD2 = (const float*)d_in[11];
    const float* We2   = (const float*)d_in[12];
    const float* attE2 = (const float*)d_in[13];
    const float* b2    = (const float*)d_in[14];
    float* out = (float*)d_out;
    const int* src = ei;
    const int* dst = ei + N_EDGES;

    char* p = (char*)d_ws;
    auto alloc = [&](size_t bytes) { char* r = p; p += (bytes + 255) & ~(size_t)255; return r; };
    __hip_bfloat16* xh1b = (__hip_bfloat16*)alloc((size_t)N_NODES * 128 * 2);  // 25.6 MB
    float* h1       = (float*)alloc((size_t)N_NODES * 128 * 4);                // 51.2 MB
    float* ew1c     = (float*)alloc((size_t)N_EDGES * 8 * 4);                  // 51.2 MB
    float* ae2c     = (float*)alloc((size_t)N_EDGES * 4);                      // 6.4 MB
    int*   srcc     = (int*)alloc((size_t)N_EDGES * 4);                        // 6.4 MB
    float* xh2      = (float*)alloc((size_t)N_NODES * 16 * 4);                 // 6.4 MB
    float* a2s      = (float*)alloc((size_t)N_NODES * 4);
    float* a2d      = (float*)alloc((size_t)N_NODES * 4);
    float* a1s      = (float*)alloc((size_t)N_NODES * 8 * 4);
    float* a1d      = (float*)alloc((size_t)N_NODES * 8 * 4);
    int*   eid      = (int*)alloc((size_t)N_EDGES * 4);                        // 6.4 MB
    int*   count    = (int*)alloc((size_t)N_NODES * 4);
    int*   cursor   = (int*)alloc((size_t)N_NODES * 4);   // contiguous after count
    int*   offs     = (int*)alloc((size_t)(N_NODES + 1) * 4);
    int*   partials = (int*)alloc(1024 * 4);
    float* M1       = (float*)alloc(128 * 4);
    float* M2       = (float*)alloc(64 * 4);
    if ((size_t)(p - (char*)d_ws) > ws_size) return;  // workspace too small — fail visibly

    const int nb_scan = (N_NODES + 255) / 256;  // 391

    hipMemsetAsync(count, 0, (size_t)2 * N_NODES * 4 + 256, stream);  // count + cursor
    k_pre<<<1, 192, 0, stream>>>(We1, attE1, We2, attE2, M1, M2);
    k_gemm1<<<(N_NODES + 63) / 64, 256, 0, stream>>>(x, W1, attS1, attD1, xh1b, a1s, a1d);
    k_hist<<<(N_EDGES + 255) / 256, 256, 0, stream>>>(dst, count);
    k_scan1<<<nb_scan, 256, 0, stream>>>(count, offs, partials);
    k_scan2<<<1, 512, 0, stream>>>(partials, nb_scan);
    k_scan3<<<nb_scan, 256, 0, stream>>>(offs, partials);
    k_scatter<<<N_EDGES / 256, 256, 0, stream>>>(dst, offs, cursor, eid);
    k_attn<<<N_EDGES / 256, 256, 0, stream>>>(eid, src, dst, ea, M1, M2, a1s, a1d,
                                              ew1c, ae2c, srcc);
    k_agg1<<<N_NODES, 128, 0, stream>>>(srcc, ew1c, xh1b, offs, count, b1, h1);
    k_gemm2<<<N_NODES / 16, 256, 0, stream>>>(h1, W2, attS2, attD2, xh2, a2s, a2d);
    k_agg2<<<N_NODES, 64, 0, stream>>>(srcc, ae2c, a2s, a2d, xh2, offs, count, b2, out);
}

// Round 5
// 635.083 us; speedup vs baseline: 1.3404x; 1.0687x over previous
//
#include <hip/hip_runtime.h>
#include <hip/hip_bf16.h>

#define N_NODES 100000
#define N_EDGES 1600000
#define NEG_SLOPE 0.2f
#define LDS_STRIDE 132

typedef __attribute__((ext_vector_type(8))) short short8;
typedef __attribute__((ext_vector_type(4))) short short4v;
typedef __attribute__((ext_vector_type(4))) float floatx4;

__device__ inline short f2bf(float f) {
    __hip_bfloat16 h = __float2bfloat16(f);
    return *reinterpret_cast<short*>(&h);
}
__device__ inline float bf2f(unsigned short u) {
    union { unsigned int i; float f; } z; z.i = ((unsigned int)u) << 16; return z.f;
}

// ---------------- precompute M1[16][8], M2[16] ----------------
__global__ void k_pre(const float* __restrict__ We1, const float* __restrict__ attE1,
                      const float* __restrict__ We2, const float* __restrict__ attE2,
                      float* __restrict__ M1, float* __restrict__ M2) {
    int t = threadIdx.x;
    if (t < 128) {
        int d = t >> 3, h = t & 7;
        float s = 0.f;
        for (int c = 0; c < 16; ++c) s += We1[d * 128 + h * 16 + c] * attE1[h * 16 + c];
        M1[d * 8 + h] = s;   // layout [d][h]
    } else if (t < 144) {
        int d = t - 128;
        float s = 0.f;
        for (int c = 0; c < 16; ++c) s += We2[d * 16 + c] * attE2[c];
        M2[d] = s;
    }
}

// ---------------- GEMM1 via bf16 MFMA: xh1b (bf16) + a1s/a1d (fp32) ----------------
__global__ __launch_bounds__(256) void k_gemm1(
    const float* __restrict__ x, const float* __restrict__ W1,
    const float* __restrict__ attS, const float* __restrict__ attD,
    __hip_bfloat16* __restrict__ xh1b, float* __restrict__ a1s, float* __restrict__ a1d) {
    __shared__ short lds[128 * LDS_STRIDE];   // W1^T bf16 [n][k], later reused for out-tile
    int t = threadIdx.x;
    for (int i = t * 4; i < 16384; i += 1024) {
        float4 v = *(const float4*)(W1 + i);
        int k = i >> 7, n = i & 127;
        lds[(n + 0) * LDS_STRIDE + k] = f2bf(v.x);
        lds[(n + 1) * LDS_STRIDE + k] = f2bf(v.y);
        lds[(n + 2) * LDS_STRIDE + k] = f2bf(v.z);
        lds[(n + 3) * LDS_STRIDE + k] = f2bf(v.w);
    }
    __syncthreads();
    int w = t >> 6, l = t & 63;
    int q = l >> 4, m = l & 15;
    int row = blockIdx.x * 64 + w * 16 + m;
    int rowc = row < N_NODES ? row : 0;
    floatx4 acc[8];
#pragma unroll
    for (int nt = 0; nt < 8; ++nt) acc[nt] = (floatx4){0.f, 0.f, 0.f, 0.f};
#pragma unroll
    for (int KK = 0; KK < 4; ++KK) {
        int k0 = KK * 32 + q * 8;
        float4 alo = *(const float4*)(x + (size_t)rowc * 128 + k0);
        float4 ahi = *(const float4*)(x + (size_t)rowc * 128 + k0 + 4);
        short8 a = {f2bf(alo.x), f2bf(alo.y), f2bf(alo.z), f2bf(alo.w),
                    f2bf(ahi.x), f2bf(ahi.y), f2bf(ahi.z), f2bf(ahi.w)};
#pragma unroll
        for (int nt = 0; nt < 8; ++nt) {
            const short* bp = &lds[(nt * 16 + m) * LDS_STRIDE + k0];
            short4v blo = *(const short4v*)bp;
            short4v bhi = *(const short4v*)(bp + 4);
            short8 b = {blo.x, blo.y, blo.z, blo.w, bhi.x, bhi.y, bhi.z, bhi.w};
            acc[nt] = __builtin_amdgcn_mfma_f32_16x16x32_bf16(a, b, acc[nt], 0, 0, 0);
        }
    }
    int rb = blockIdx.x * 64 + w * 16 + q * 4;
#pragma unroll
    for (int nt = 0; nt < 8; ++nt) {
        float aS = attS[nt * 16 + m], aD = attD[nt * 16 + m];
        float p0 = acc[nt][0] * aS, p1 = acc[nt][1] * aS, p2 = acc[nt][2] * aS, p3 = acc[nt][3] * aS;
        float d0 = acc[nt][0] * aD, d1 = acc[nt][1] * aD, d2 = acc[nt][2] * aD, d3 = acc[nt][3] * aD;
        for (int dd = 1; dd < 16; dd <<= 1) {
            p0 += __shfl_xor(p0, dd); p1 += __shfl_xor(p1, dd);
            p2 += __shfl_xor(p2, dd); p3 += __shfl_xor(p3, dd);
            d0 += __shfl_xor(d0, dd); d1 += __shfl_xor(d1, dd);
            d2 += __shfl_xor(d2, dd); d3 += __shfl_xor(d3, dd);
        }
        if (m == 0) {
            if (rb + 0 < N_NODES) { a1s[(size_t)(rb+0)*8+nt] = p0; a1d[(size_t)(rb+0)*8+nt] = d0; }
            if (rb + 1 < N_NODES) { a1s[(size_t)(rb+1)*8+nt] = p1; a1d[(size_t)(rb+1)*8+nt] = d1; }
            if (rb + 2 < N_NODES) { a1s[(size_t)(rb+2)*8+nt] = p2; a1d[(size_t)(rb+2)*8+nt] = d2; }
            if (rb + 3 < N_NODES) { a1s[(size_t)(rb+3)*8+nt] = p3; a1d[(size_t)(rb+3)*8+nt] = d3; }
        }
    }
    __syncthreads();
#pragma unroll
    for (int nt = 0; nt < 8; ++nt) {
#pragma unroll
        for (int r = 0; r < 4; ++r)
            lds[(w * 16 + q * 4 + r) * LDS_STRIDE + nt * 16 + m] = f2bf(acc[nt][r]);
    }
    __syncthreads();
    int r2 = t >> 2, c2 = (t & 3) * 32;
    int gr = blockIdx.x * 64 + r2;
    if (gr < N_NODES) {
        short* gp = (short*)(xh1b + (size_t)gr * 128 + c2);
#pragma unroll
        for (int i = 0; i < 8; ++i)
            *(short4v*)(gp + i * 4) = *(const short4v*)&lds[r2 * LDS_STRIDE + c2 + i * 4];
    }
}

// ---------------- CSR build ----------------
__global__ void k_hist(const int* __restrict__ dst, int* __restrict__ count) {
    int i = blockIdx.x * blockDim.x + threadIdx.x;
    if (i < N_EDGES) atomicAdd(&count[dst[i]], 1);
}

__global__ __launch_bounds__(256) void k_scan1(const int* __restrict__ count,
                                               int* __restrict__ offs, int* __restrict__ partials) {
    __shared__ int s[256];
    int t = threadIdx.x;
    int i = blockIdx.x * 256 + t;
    int v = (i < N_NODES) ? count[i] : 0;
    s[t] = v; __syncthreads();
    for (int off = 1; off < 256; off <<= 1) {
        int add = (t >= off) ? s[t - off] : 0;
        __syncthreads();
        s[t] += add; __syncthreads();
    }
    if (i < N_NODES) offs[i] = s[t] - v;
    if (t == 255) partials[blockIdx.x] = s[255];
}

__global__ __launch_bounds__(512) void k_scan2(int* __restrict__ partials, int nb) {
    __shared__ int s[512];
    int t = threadIdx.x;
    int v = (t < nb) ? partials[t] : 0;
    s[t] = v; __syncthreads();
    for (int off = 1; off < 512; off <<= 1) {
        int add = (t >= off) ? s[t - off] : 0;
        __syncthreads();
        s[t] += add; __syncthreads();
    }
    if (t < nb) partials[t] = s[t] - v;
}

__global__ void k_scan3(int* __restrict__ offs, const int* __restrict__ partials) {
    int i = blockIdx.x * 256 + threadIdx.x;
    if (i < N_NODES) offs[i] += partials[blockIdx.x];
}

// ---------------- k_scatter: {e, src[e]} 8-byte permutation scatter ----------------
__global__ __launch_bounds__(256) void k_scatter(
    const int* __restrict__ src, const int* __restrict__ dst, const int* __restrict__ offs,
    int* __restrict__ cursor, int2* __restrict__ pes) {
    int e = blockIdx.x * 256 + threadIdx.x;
    int d = dst[e];
    int s = src[e];
    int p = offs[d] + atomicAdd(&cursor[d], 1);
    int2 v; v.x = e; v.y = s;
    pes[p] = v;
}

// ---------------- k_fill: dstc[p] = owning node (CSR segment id) ----------------
__global__ __launch_bounds__(256) void k_fill(
    const int* __restrict__ offs, const int* __restrict__ count, int* __restrict__ dstc) {
    int n = blockIdx.x * 256 + threadIdx.x;
    if (n >= N_NODES) return;
    int s = offs[n], e = s + count[n];
    for (int i = s; i < e; ++i) dstc[i] = n;
}

// ---------------- k_attn: CSR-order; only random access is the ea line gather ----------------
__global__ __launch_bounds__(256) void k_attn(
    const int2* __restrict__ pes, const int* __restrict__ dstc,
    const float* __restrict__ ea, const float* __restrict__ M1, const float* __restrict__ M2,
    const float* __restrict__ a1s, const float* __restrict__ a1d,
    float* __restrict__ ew1c, float* __restrict__ ae2c, int* __restrict__ srcc) {
    __shared__ float M1s[128], M2s[16];
    int t = threadIdx.x;
    if (t < 128) M1s[t] = M1[t];
    if (t >= 128 && t < 144) M2s[t - 128] = M2[t - 128];
    __syncthreads();
    int p = blockIdx.x * 256 + t;
    int2 es = pes[p];
    int e = es.x, s = es.y;
    int d = dstc[p];                      // near-uniform across adjacent lanes -> broadcast
    float eav[16];
#pragma unroll
    for (int qq = 0; qq < 4; ++qq) {
        float4 v = *(const float4*)(ea + (size_t)e * 16 + qq * 4);
        eav[qq * 4] = v.x; eav[qq * 4 + 1] = v.y; eav[qq * 4 + 2] = v.z; eav[qq * 4 + 3] = v.w;
    }
    float ae1[8];
#pragma unroll
    for (int h = 0; h < 8; ++h) ae1[h] = 0.f;
#pragma unroll
    for (int dd = 0; dd < 16; ++dd) {
#pragma unroll
        for (int h = 0; h < 8; ++h) ae1[h] += eav[dd] * M1s[dd * 8 + h];
    }
    float aes = 0.f;
#pragma unroll
    for (int dd = 0; dd < 16; ++dd) aes += eav[dd] * M2s[dd];
    float4 s0 = *(const float4*)(a1s + (size_t)s * 8);
    float4 s1 = *(const float4*)(a1s + (size_t)s * 8 + 4);
    float4 d0 = *(const float4*)(a1d + (size_t)d * 8);
    float4 d1 = *(const float4*)(a1d + (size_t)d * 8 + 4);
    float as_[8] = {s0.x, s0.y, s0.z, s0.w, s1.x, s1.y, s1.z, s1.w};
    float ad_[8] = {d0.x, d0.y, d0.z, d0.w, d1.x, d1.y, d1.z, d1.w};
    float ew[8];
#pragma unroll
    for (int h = 0; h < 8; ++h) {
        float v = as_[h] + ad_[h] + ae1[h];
        v = v > 0.f ? v : NEG_SLOPE * v;
        ew[h] = __expf(v);
    }
    float4 w0 = {ew[0], ew[1], ew[2], ew[3]};
    float4 w1 = {ew[4], ew[5], ew[6], ew[7]};
    *(float4*)(ew1c + (size_t)p * 8) = w0;
    *(float4*)(ew1c + (size_t)p * 8 + 4) = w1;
    ae2c[p] = aes;
    srcc[p] = s;
}

// ---------------- layer-1 aggregation: bf16 row gathers ----------------
__global__ __launch_bounds__(128) void k_agg1(
    const int* __restrict__ srcc, const float* __restrict__ ew1c,
    const __hip_bfloat16* __restrict__ xh1b, const int* __restrict__ offs,
    const int* __restrict__ count, const float* __restrict__ b1, float* __restrict__ h1) {
    __shared__ float4 racc[32];
    __shared__ float rw[32];
    int n = blockIdx.x;
    int t = threadIdx.x;
    int j = t & 31, k = t >> 5;
    int start = offs[n], deg = count[n];
    float4 acc = {0.f, 0.f, 0.f, 0.f};
    float wsum = 0.f;
    int i = k;
    int s = 0; float w = 0.f;
    if (i < deg) {
        int p = start + i;
        s = srcc[p];
        w = ew1c[(size_t)p * 8 + (j >> 2)];
    }
    while (i < deg) {
        int ni = i + 4;
        int ns = 0; float nw = 0.f;
        if (ni < deg) {
            int np = start + ni;
            ns = srcc[np];
            nw = ew1c[(size_t)np * 8 + (j >> 2)];
        }
        uint2 xv = *(const uint2*)((const char*)xh1b + (size_t)s * 256 + j * 8);
        float x0 = bf2f((unsigned short)(xv.x & 0xffff));
        float x1 = bf2f((unsigned short)(xv.x >> 16));
        float x2 = bf2f((unsigned short)(xv.y & 0xffff));
        float x3 = bf2f((unsigned short)(xv.y >> 16));
        acc.x += w * x0; acc.y += w * x1; acc.z += w * x2; acc.w += w * x3;
        wsum += w;
        i = ni; s = ns; w = nw;
    }
    acc.x += __shfl_xor(acc.x, 32); acc.y += __shfl_xor(acc.y, 32);
    acc.z += __shfl_xor(acc.z, 32); acc.w += __shfl_xor(acc.w, 32);
    wsum += __shfl_xor(wsum, 32);
    if (t >= 64 && t < 96) { racc[j] = acc; rw[j] = wsum; }
    __syncthreads();
    if (t < 32) {
        float4 o = racc[j];
        acc.x += o.x; acc.y += o.y; acc.z += o.z; acc.w += o.w;
        wsum += rw[j];
        float inv = 1.f / (wsum + 1e-16f);
        float4 b = *(const float4*)(b1 + j * 4);
        float4 r;
        r.x = acc.x * inv + b.x; r.y = acc.y * inv + b.y;
        r.z = acc.z * inv + b.z; r.w = acc.w * inv + b.w;
        r.x = r.x > 0.f ? r.x : __expf(r.x) - 1.f;
        r.y = r.y > 0.f ? r.y : __expf(r.y) - 1.f;
        r.z = r.z > 0.f ? r.z : __expf(r.z) - 1.f;
        r.w = r.w > 0.f ? r.w : __expf(r.w) - 1.f;
        *(float4*)(h1 + (size_t)n * 128 + j * 4) = r;
    }
}

// ---------------- GEMM2: xh2 = h1 @ W2, plus a2s/a2d ----------------
__global__ __launch_bounds__(256) void k_gemm2(
    const float* __restrict__ h1, const float* __restrict__ W2,
    const float* __restrict__ attS, const float* __restrict__ attD,
    float* __restrict__ xh2, float* __restrict__ a2s, float* __restrict__ a2d) {
    __shared__ float W2s[128 * 16];
    __shared__ float hs[16 * 132];
    int t = threadIdx.x;
    for (int i = t * 4; i < 2048; i += 1024)
        *(float4*)(W2s + i) = *(const float4*)(W2 + i);
    size_t base = (size_t)blockIdx.x * 16 * 128;
    for (int i = t * 4; i < 2048; i += 1024) {
        float4 v = *(const float4*)(h1 + base + i);
        int r = i >> 7, k = i & 127;
        float* dstp = hs + r * 132 + k;
        dstp[0] = v.x; dstp[1] = v.y; dstp[2] = v.z; dstp[3] = v.w;
    }
    __syncthreads();
    int r = t >> 4, c = t & 15;
    float acc = 0.f;
#pragma unroll 4
    for (int k = 0; k < 128; ++k) acc += hs[r * 132 + k] * W2s[k * 16 + c];
    int row = blockIdx.x * 16 + r;
    xh2[(size_t)row * 16 + c] = acc;
    float ps = acc * attS[c], pd = acc * attD[c];
#pragma unroll
    for (int m = 1; m < 16; m <<= 1) { ps += __shfl_xor(ps, m); pd += __shfl_xor(pd, m); }
    if (c == 0) { a2s[row] = ps; a2d[row] = pd; }
}

// ---------------- layer-2 aggregation + bias + log_softmax ----------------
__global__ __launch_bounds__(64) void k_agg2(
    const int* __restrict__ srcc, const float* __restrict__ ae2c,
    const float* __restrict__ a2s, const float* __restrict__ a2d, const float* __restrict__ xh2,
    const int* __restrict__ offs, const int* __restrict__ count,
    const float* __restrict__ b2, float* __restrict__ out) {
    int n = blockIdx.x;
    int t = threadIdx.x;
    int l = t & 3, k = t >> 2;
    int start = offs[n], deg = count[n];
    float ad = a2d[n];
    float4 acc = {0.f, 0.f, 0.f, 0.f};
    float wsum = 0.f;
    for (int i = k; i < deg; i += 16) {
        int p = start + i;
        int s = srcc[p];
        float lg = a2s[s] + ad + ae2c[p];
        lg = lg > 0.f ? lg : NEG_SLOPE * lg;
        float w = __expf(lg);
        float4 xv = *(const float4*)(xh2 + (size_t)s * 16 + l * 4);
        acc.x += w * xv.x; acc.y += w * xv.y; acc.z += w * xv.z; acc.w += w * xv.w;
        wsum += w;
    }
#pragma unroll
    for (int m = 4; m < 64; m <<= 1) {
        acc.x += __shfl_xor(acc.x, m); acc.y += __shfl_xor(acc.y, m);
        acc.z += __shfl_xor(acc.z, m); acc.w += __shfl_xor(acc.w, m);
        wsum += __shfl_xor(wsum, m);
    }
    float inv = 1.f / (wsum + 1e-16f);
    float4 b = *(const float4*)(b2 + l * 4);
    float4 lo;
    lo.x = acc.x * inv + b.x; lo.y = acc.y * inv + b.y;
    lo.z = acc.z * inv + b.z; lo.w = acc.w * inv + b.w;
    float mx = fmaxf(fmaxf(lo.x, lo.y), fmaxf(lo.z, lo.w));
    mx = fmaxf(mx, __shfl_xor(mx, 1)); mx = fmaxf(mx, __shfl_xor(mx, 2));
    float ex = __expf(lo.x - mx) + __expf(lo.y - mx) + __expf(lo.z - mx) + __expf(lo.w - mx);
    ex += __shfl_xor(ex, 1); ex += __shfl_xor(ex, 2);
    float ls = mx + __logf(ex);
    if (t < 4) {
        float4 r = {lo.x - ls, lo.y - ls, lo.z - ls, lo.w - ls};
        *(float4*)(out + (size_t)n * 16 + l * 4) = r;
    }
}

extern "C" void kernel_launch(void* const* d_in, const int* in_sizes, int n_in,
                              void* d_out, int out_size, void* d_ws, size_t ws_size,
                              hipStream_t stream) {
    const float* x     = (const float*)d_in[0];
    const int*   ei    = (const int*)d_in[1];
    const float* ea    = (const float*)d_in[2];
    const float* W1    = (const float*)d_in[3];
    const float* attS1 = (const float*)d_in[4];
    const float* attD1 = (const float*)d_in[5];
    const float* We1   = (const float*)d_in[6];
    const float* attE1 = (const float*)d_in[7];
    const float* b1    = (const float*)d_in[8];
    const float* W2    = (const float*)d_in[9];
    const float* attS2 = (const float*)d_in[10];
    const float* attD2 = (const float*)d_in[11];
    const float* We2   = (const float*)d_in[12];
    const float* attE2 = (const float*)d_in[13];
    const float* b2    = (const float*)d_in[14];
    float* out = (float*)d_out;
    const int* src = ei;
    const int* dst = ei + N_EDGES;

    char* p = (char*)d_ws;
    auto alloc = [&](size_t bytes) { char* r = p; p += (bytes + 255) & ~(size_t)255; return r; };
    __hip_bfloat16* xh1b = (__hip_bfloat16*)alloc((size_t)N_NODES * 128 * 2);  // 25.6 MB
    float* h1       = (float*)alloc((size_t)N_NODES * 128 * 4);                // 51.2 MB
    float* ew1c     = (float*)alloc((size_t)N_EDGES * 8 * 4);                  // 51.2 MB
    float* ae2c     = (float*)alloc((size_t)N_EDGES * 4);                      // 6.4 MB
    int*   srcc     = (int*)alloc((size_t)N_EDGES * 4);                        // 6.4 MB
    int2*  pes      = (int2*)alloc((size_t)N_EDGES * 8);                       // 12.8 MB
    int*   dstc     = (int*)alloc((size_t)N_EDGES * 4);                        // 6.4 MB
    float* xh2      = (float*)alloc((size_t)N_NODES * 16 * 4);                 // 6.4 MB
    float* a2s      = (float*)alloc((size_t)N_NODES * 4);
    float* a2d      = (float*)alloc((size_t)N_NODES * 4);
    float* a1s      = (float*)alloc((size_t)N_NODES * 8 * 4);
    float* a1d      = (float*)alloc((size_t)N_NODES * 8 * 4);
    int*   count    = (int*)alloc((size_t)N_NODES * 4);
    int*   cursor   = (int*)alloc((size_t)N_NODES * 4);   // contiguous after count
    int*   offs     = (int*)alloc((size_t)(N_NODES + 1) * 4);
    int*   partials = (int*)alloc(1024 * 4);
    float* M1       = (float*)alloc(128 * 4);
    float* M2       = (float*)alloc(64 * 4);
    if ((size_t)(p - (char*)d_ws) > ws_size) return;  // workspace too small — fail visibly

    const int nb_scan = (N_NODES + 255) / 256;  // 391

    hipMemsetAsync(count, 0, (size_t)2 * N_NODES * 4 + 256, stream);  // count + cursor
    k_pre<<<1, 192, 0, stream>>>(We1, attE1, We2, attE2, M1, M2);
    k_gemm1<<<(N_NODES + 63) / 64, 256, 0, stream>>>(x, W1, attS1, attD1, xh1b, a1s, a1d);
    k_hist<<<(N_EDGES + 255) / 256, 256, 0, stream>>>(dst, count);
    k_scan1<<<nb_scan, 256, 0, stream>>>(count, offs, partials);
    k_scan2<<<1, 512, 0, stream>>>(partials, nb_scan);
    k_scan3<<<nb_scan, 256, 0, stream>>>(offs, partials);
    k_scatter<<<N_EDGES / 256, 256, 0, stream>>>(src, dst, offs, cursor, pes);
    k_fill<<<nb_scan, 256, 0, stream>>>(offs, count, dstc);
    k_attn<<<N_EDGES / 256, 256, 0, stream>>>(pes, dstc, ea, M1, M2, a1s, a1d,
                                              ew1c, ae2c, srcc);
    k_agg1<<<N_NODES, 128, 0, stream>>>(srcc, ew1c, xh1b, offs, count, b1, h1);
    k_gemm2<<<N_NODES / 16, 256, 0, stream>>>(h1, W2, attS2, attD2, xh2, a2s, a2d);
    k_agg2<<<N_NODES, 64, 0, stream>>>(srcc, ae2c, a2s, a2d, xh2, offs, count, b2, out);
}